// Round 7
// baseline (2144.590 us; speedup 1.0000x reference)
//
#include <hip/hip_runtime.h>

#define B_  4
#define S_  2048
#define D_  768
#define NH_ 4
#define DH_ 192

typedef short  s8v __attribute__((ext_vector_type(8)));
typedef float  f4v __attribute__((ext_vector_type(4)));
typedef unsigned short ushort_t;

static __device__ __forceinline__ ushort_t f2bf(float f) {
    union { float f; unsigned u; } v; v.f = f;
    unsigned r = v.u + 0x7fffu + ((v.u >> 16) & 1u);
    return (ushort_t)(r >> 16);
}
static __device__ __forceinline__ float bf2f(ushort_t b) {
    union { unsigned u; float f; } v; v.u = ((unsigned)b) << 16;
    return v.f;
}
static __device__ __forceinline__ f4v mfma16(s8v a, s8v b, f4v c) {
    return __builtin_amdgcn_mfma_f32_16x16x32_bf16(a, b, c, 0, 0, 0);
}
// packed-bf16 dot2 into f32: D = a.lo*b.lo + a.hi*b.hi + c  (full vector rate)
static __device__ __forceinline__ float dot2bf(unsigned a, unsigned b, float c) {
    float d;
    asm("v_dot2_f32_bf16 %0, %1, %2, %3" : "=v"(d) : "v"(a), "v"(b), "v"(c));
    return d;
}
// sum across the 4 lanes of a quad (DPP quad_perm; pure VALU, no LDS pipe)
static __device__ __forceinline__ float qsum(float x) {
    union { float f; int i; } u, v;
    u.f = x;
    v.i = __builtin_amdgcn_mov_dpp(u.i, 0xB1, 0xF, 0xF, true);  // [1,0,3,2]
    x += v.f;
    u.f = x;
    v.i = __builtin_amdgcn_mov_dpp(u.i, 0x4E, 0xF, 0xF, true);  // [2,3,0,1]
    x += v.f;
    return x;
}

// ---------------------------------------------------------------------------
// Kernel 1: causal depthwise conv1d + swish -> x_conv (bf16); also x -> bf16.
// ---------------------------------------------------------------------------
__global__ void conv_kernel(const float* __restrict__ x, const float* __restrict__ ck,
                            const float* __restrict__ cb,
                            ushort_t* __restrict__ xconv, ushort_t* __restrict__ xb) {
    int idx = blockIdx.x * blockDim.x + threadIdx.x;   // over B*S*D/4
    const int nd4 = D_ / 4;
    int d4 = idx % nd4;
    int bs = idx / nd4;
    int s = bs % S_;
    int b = bs / S_;
    int d = d4 * 4;

    float4 acc = *(const float4*)(cb + d);
    float4 xcur = make_float4(0.f, 0.f, 0.f, 0.f);
#pragma unroll
    for (int k = 0; k < 4; ++k) {
        int sk = s - 3 + k;
        float4 xv = make_float4(0.f, 0.f, 0.f, 0.f);
        if (sk >= 0) xv = *(const float4*)(x + ((size_t)(b * S_ + sk) * D_ + d));
        if (k == 3) xcur = xv;
        float4 kv = *(const float4*)(ck + (size_t)k * D_ + d);
        acc.x += xv.x * kv.x; acc.y += xv.y * kv.y;
        acc.z += xv.z * kv.z; acc.w += xv.w * kv.w;
    }
    float c0 = acc.x / (1.f + __expf(-acc.x));
    float c1 = acc.y / (1.f + __expf(-acc.y));
    float c2 = acc.z / (1.f + __expf(-acc.z));
    float c3 = acc.w / (1.f + __expf(-acc.w));

    size_t base = (size_t)bs * D_ + d;
    ushort4 pc; pc.x = f2bf(c0); pc.y = f2bf(c1); pc.z = f2bf(c2); pc.w = f2bf(c3);
    *(ushort4*)(xconv + base) = pc;
    ushort4 px; px.x = f2bf(xcur.x); px.y = f2bf(xcur.y); px.z = f2bf(xcur.z); px.w = f2bf(xcur.w);
    *(ushort4*)(xb + base) = px;
}

// ---------------------------------------------------------------------------
// Kernel 2: gate pre-activation GEMMs (unchanged).
// G layout: [s][h][b][e][g] bf16 (g in {i,f,z,o}), cell_bias folded in.
// ---------------------------------------------------------------------------
__launch_bounds__(768)
__global__ void gates_kernel(const ushort_t* __restrict__ xconv, const ushort_t* __restrict__ xb,
                             const float* __restrict__ Wi, const float* __restrict__ Wf,
                             const float* __restrict__ Wz, const float* __restrict__ Wo,
                             const float* __restrict__ cbias, ushort_t* __restrict__ G) {
    int sb = blockIdx.x, h = blockIdx.y, p = blockIdx.z;
    const ushort_t* X = (p == 0) ? xconv : xb;
    const float* W0 = (p == 0) ? Wi : Wz;
    const float* W1 = (p == 0) ? Wf : Wo;

    int tid = threadIdx.x;
    int lane = tid & 63;
    int w = tid >> 6;                 // 0..11 = e-tile

    int col = w * 16 + (lane & 15);   // e
    int kq0 = (lane >> 4) * 8;

    s8v B0[6], B1[6];
#pragma unroll
    for (int kt = 0; kt < 6; ++kt) {
        const float* w0p = W0 + ((size_t)(h * DH_ + kt * 32 + kq0)) * DH_ + col;
        const float* w1p = W1 + ((size_t)(h * DH_ + kt * 32 + kq0)) * DH_ + col;
        s8v f0, f1;
#pragma unroll
        for (int j = 0; j < 8; ++j) {
            f0[j] = (short)f2bf(w0p[(size_t)j * DH_]);
            f1[j] = (short)f2bf(w1p[(size_t)j * DH_]);
        }
        B0[kt] = f0; B1[kt] = f1;
    }
    float bias0 = cbias[(size_t)(2 * p) * D_ + h * DH_ + col];
    float bias1 = cbias[(size_t)(2 * p + 1) * D_ + h * DH_ + col];

    int b_l = lane & 3;
    int ds_l = (lane >> 2) & 3;

    for (int mt = 0; mt < 16; ++mt) {
        int s = sb * 64 + mt * 4 + ds_l;
        const ushort_t* ap = X + ((size_t)(b_l * S_ + s) * D_ + h * DH_ + kq0);
        s8v A[6];
#pragma unroll
        for (int kt = 0; kt < 6; ++kt) A[kt] = *(const s8v*)(ap + kt * 32);
        f4v a0 = {0.f, 0.f, 0.f, 0.f}, a1 = {0.f, 0.f, 0.f, 0.f};
#pragma unroll
        for (int kt = 0; kt < 6; ++kt) {
            a0 = mfma16(A[kt], B0[kt], a0);
            a1 = mfma16(A[kt], B1[kt], a1);
        }
        int sro = sb * 64 + mt * 4 + (lane >> 4);
#pragma unroll
        for (int r = 0; r < 4; ++r) {
            size_t idx = (((size_t)(sro * NH_ + h) * B_ + r) * DH_ + col) * 4;
            ushort2 pr;
            pr.x = f2bf(a0[r] + bias0);
            pr.y = f2bf(a1[r] + bias1);
            *(ushort2*)(G + idx + 2 * p) = pr;
        }
    }
}

// ---------------------------------------------------------------------------
// Kernel 3: sequential recurrence, v_dot2_f32_bf16, d-split + quad-reduce.
//
// Remat saga: VGPR_Count was 84/64/72 across R3/R4/R6 -- always far below the
// 96 R dwords per lane. R6 proved the waves_per_eu(3,3) clamp applied (SGPR
// changed) yet the allocator STILL re-derived R every step: loads from
// loop-invariant addresses are trivially rematerializable, and RA splits
// live-through-loop ranges regardless of the occupancy budget. A pre-loop
// PIN doesn't help ("+v" binds only at the asm point).
//
// Fix: RPIN() INSIDE the loop. An empty volatile asm with "+v" per value,
// executed every iteration, makes the reaching definition an opaque asm ->
// NOT rematerializable, NOT hoistable. Zero instructions emitted. The only
// legal alternatives for RA are full residency (what we want) or scratch
// spill (visible as a big regression -> kills the path definitively).
//
// Structure (unchanged from R3/R4/R6):
//  - 16 WGs (one per (b,h)), 768 thr = 12 waves = exactly 3 waves/SIMD;
//    dot2 issue floor = 147456 MACs / 256 MACs/cyc = 576 cyc/step.
//  - thread = (e, q=lane&3) owns d-quarter q of all 4 gates' R columns:
//    24 NAMED uint4 = 96 dwords.
//  - h reads are quad-broadcast (16 same-address lanes/wave) -> conflict-free.
//  - quad partials reduced with 2 mov_dpp quad_perm + adds; gating redundant
//    across quad lanes; leader writes h (LDS) + ys (global).
//  - 2-deep G prefetch; one lgkm-only barrier per step.
// ys layout: [s][h][b][e] bf16.
// VERIFY GATE: VGPR_Count >= 128 and recur < 1531 us, else revert to R1.
// ---------------------------------------------------------------------------
#define PACK1(rp, j) ((unsigned)f2bf((rp)[(size_t)(2 * (j)) * DH_]) | \
                      ((unsigned)f2bf((rp)[(size_t)(2 * (j) + 1) * DH_]) << 16))
#define LDK(rp, k) make_uint4(PACK1(rp, 4 * (k)), PACK1(rp, 4 * (k) + 1), \
                              PACK1(rp, 4 * (k) + 2), PACK1(rp, 4 * (k) + 3))
// Opaque register pin: result of an asm can't be rematerialized.
#define PIN4(V) asm volatile("" : "+v"(V.x), "+v"(V.y), "+v"(V.z), "+v"(V.w))
// Re-pin all R registers every loop iteration: defeats RA live-range
// splitting via remat (the def is now an opaque, iteration-local asm).
#define RPIN() do { \
    PIN4(Ri0); PIN4(Ri1); PIN4(Ri2); PIN4(Ri3); PIN4(Ri4); PIN4(Ri5); \
    PIN4(Rf0); PIN4(Rf1); PIN4(Rf2); PIN4(Rf3); PIN4(Rf4); PIN4(Rf5); \
    PIN4(Rz0); PIN4(Rz1); PIN4(Rz2); PIN4(Rz3); PIN4(Rz4); PIN4(Rz5); \
    PIN4(Ro0); PIN4(Ro1); PIN4(Ro2); PIN4(Ro3); PIN4(Ro4); PIN4(Ro5); \
} while (0)

#define DOTK(H, RI, RF, RZ, RO) do { \
    ai = dot2bf(H.x, RI.x, ai); af = dot2bf(H.x, RF.x, af); \
    az = dot2bf(H.x, RZ.x, az); ao = dot2bf(H.x, RO.x, ao); \
    ai = dot2bf(H.y, RI.y, ai); af = dot2bf(H.y, RF.y, af); \
    az = dot2bf(H.y, RZ.y, az); ao = dot2bf(H.y, RO.y, ao); \
    ai = dot2bf(H.z, RI.z, ai); af = dot2bf(H.z, RF.z, af); \
    az = dot2bf(H.z, RZ.z, az); ao = dot2bf(H.z, RO.z, ao); \
    ai = dot2bf(H.w, RI.w, ai); af = dot2bf(H.w, RF.w, af); \
    az = dot2bf(H.w, RZ.w, az); ao = dot2bf(H.w, RO.w, ao); \
} while (0)

#define STEP(p) do { \
    const uint4* hbp = (const uint4*)((const char*)h_lds + (p) * 384 + q * 96); \
    uint4 H0 = hbp[0], H1 = hbp[1], H2 = hbp[2], H3 = hbp[3], H4 = hbp[4], H5 = hbp[5]; \
    float ai = 0.f, af = 0.f, az = 0.f, ao = 0.f; \
    DOTK(H0, Ri0, Rf0, Rz0, Ro0); \
    DOTK(H1, Ri1, Rf1, Rz1, Ro1); \
    DOTK(H2, Ri2, Rf2, Rz2, Ro2); \
    DOTK(H3, Ri3, Rf3, Rz3, Ro3); \
    DOTK(H4, Ri4, Rf4, Rz4, Ro4); \
    DOTK(H5, Ri5, Rf5, Rz5, Ro5); \
    ai = qsum(ai); af = qsum(af); az = qsum(az); ao = qsum(ao); \
    ushort4 gv = gv_n; gv_n = gv_n2; \
    gv_n2 = *(const ushort4*)gp; gp += gstride; \
    ai += bf2f(gv.x); af += bf2f(gv.y); az += bf2f(gv.z); ao += bf2f(gv.w); \
    float fm = af + m_st; \
    float mn = fmaxf(fm, ai); \
    float ia = __builtin_amdgcn_exp2f((ai - mn) * LOG2E); \
    float fa = __builtin_amdgcn_exp2f((fm - mn) * LOG2E); \
    float ez = __builtin_amdgcn_exp2f(az * (2.f * LOG2E)); \
    float th = 1.f - 2.f * __builtin_amdgcn_rcpf(ez + 1.f); \
    float cn = fa * c_st + ia * th; \
    float nn = fa * n_st + ia; \
    float sg = __builtin_amdgcn_rcpf(1.f + __builtin_amdgcn_exp2f(-ao * LOG2E)); \
    float hn = sg * cn * __builtin_amdgcn_rcpf(nn); \
    m_st = mn; c_st = cn; n_st = nn; \
    ushort_t hb16 = f2bf(hn); \
    if (qlead) h_flat[(1 - (p)) * 192 + e] = hb16; \
    asm volatile("s_waitcnt lgkmcnt(0)\n\ts_barrier" ::: "memory"); \
    if (qlead) *yp = hb16; \
    yp += ystr; \
} while (0)

__global__ void __launch_bounds__(768)
__attribute__((amdgpu_waves_per_eu(3, 3)))
recur_kernel(const ushort_t* __restrict__ G, const float* __restrict__ Rw,
             ushort_t* __restrict__ ys) {
    const int h = blockIdx.x >> 2;
    const int b = blockIdx.x & 3;
    const int tid = threadIdx.x;
    const int lane = tid & 63;
    const int w = tid >> 6;                     // 0..11
    const int e = w * 16 + (lane >> 2);         // 0..191  (column this thread serves)
    const int q = lane & 3;                     // d-quarter: d in [q*48, q*48+48)
    const bool qlead = (q == 0);

    __shared__ __align__(16) ushort_t h_lds[2][192];
    ushort_t* h_flat = &h_lds[0][0];

    // R columns for this (e, q): 4 gates x 24 packed-bf16 dwords, NAMED regs.
    const float* rp0 = Rw + ((size_t)((0 * NH_ + h) * DH_ + q * 48)) * DH_ + e;
    const float* rp1 = Rw + ((size_t)((1 * NH_ + h) * DH_ + q * 48)) * DH_ + e;
    const float* rp2 = Rw + ((size_t)((2 * NH_ + h) * DH_ + q * 48)) * DH_ + e;
    const float* rp3 = Rw + ((size_t)((3 * NH_ + h) * DH_ + q * 48)) * DH_ + e;
    uint4 Ri0 = LDK(rp0, 0), Ri1 = LDK(rp0, 1), Ri2 = LDK(rp0, 2),
          Ri3 = LDK(rp0, 3), Ri4 = LDK(rp0, 4), Ri5 = LDK(rp0, 5);
    uint4 Rf0 = LDK(rp1, 0), Rf1 = LDK(rp1, 1), Rf2 = LDK(rp1, 2),
          Rf3 = LDK(rp1, 3), Rf4 = LDK(rp1, 4), Rf5 = LDK(rp1, 5);
    uint4 Rz0 = LDK(rp2, 0), Rz1 = LDK(rp2, 1), Rz2 = LDK(rp2, 2),
          Rz3 = LDK(rp2, 3), Rz4 = LDK(rp2, 4), Rz5 = LDK(rp2, 5);
    uint4 Ro0 = LDK(rp3, 0), Ro1 = LDK(rp3, 1), Ro2 = LDK(rp3, 2),
          Ro3 = LDK(rp3, 3), Ro4 = LDK(rp3, 4), Ro5 = LDK(rp3, 5);

    if (tid < 384) h_flat[tid] = 0;

    float m_st = 0.f, c_st = 0.f, n_st = 0.f;
    const float LOG2E = 1.44269504088896f;

    const int gstride = NH_ * B_ * DH_ * 4;     // 12288 ushorts per s
    const ushort_t* gp = G + (((size_t)h * B_ + b) * DH_ + e) * 4;
    // 2-deep prefetch; over-reads at s=S_,S_+1 land in the ys region (mapped).
    ushort4 gv_n  = *(const ushort4*)gp;
    ushort4 gv_n2 = *(const ushort4*)(gp + gstride);
    gp += 2 * (size_t)gstride;

    ushort_t* yp = ys + ((size_t)h * B_ + b) * DH_ + e;
    const int ystr = NH_ * B_ * DH_;

    __syncthreads();

    for (int s = 0; s < S_; s += 2) {
        RPIN();                                 // per-iteration: defeats remat
        STEP(0);
        STEP(1);
    }
}

// ---------------------------------------------------------------------------
// Kernel 4: multi-head layernorm. One wave per (b,s,h) group of 192.
// ---------------------------------------------------------------------------
__global__ void ln_kernel(const ushort_t* __restrict__ ys, const float* __restrict__ gn,
                          float* __restrict__ out) {
    int gw = (blockIdx.x * blockDim.x + threadIdx.x) >> 6;   // 0 .. 32767
    int lane = threadIdx.x & 63;
    int b = gw & 3;
    int h = (gw >> 2) & 3;
    int s = gw >> 4;

    const ushort_t* yp = ys + (size_t)gw * DH_;
    float v0 = bf2f(yp[lane]);
    float v1 = bf2f(yp[lane + 64]);
    float v2 = bf2f(yp[lane + 128]);
    float sum = v0 + v1 + v2;
    float sq  = v0 * v0 + v1 * v1 + v2 * v2;
#pragma unroll
    for (int off = 32; off > 0; off >>= 1) {
        sum += __shfl_xor(sum, off, 64);
        sq  += __shfl_xor(sq,  off, 64);
    }
    float mu  = sum * (1.f / 192.f);
    float var = sq * (1.f / 192.f) - mu * mu;
    float rs  = rsqrtf(var + 1e-5f);

    float* op = out + (size_t)(b * S_ + s) * D_ + h * DH_;
    const float* gp = gn + h * DH_;
    op[lane]       = (v0 - mu) * rs * gp[lane];
    op[lane + 64]  = (v1 - mu) * rs * gp[lane + 64];
    op[lane + 128] = (v2 - mu) * rs * gp[lane + 128];
}

// ---------------------------------------------------------------------------
extern "C" void kernel_launch(void* const* d_in, const int* in_sizes, int n_in,
                              void* d_out, int out_size, void* d_ws, size_t ws_size,
                              hipStream_t stream) {
    const float* x     = (const float*)d_in[0];
    const float* ck    = (const float*)d_in[1];
    const float* cb    = (const float*)d_in[2];
    const float* Wi    = (const float*)d_in[3];
    const float* Wf    = (const float*)d_in[4];
    const float* Wz    = (const float*)d_in[5];
    const float* Wo    = (const float*)d_in[6];
    const float* Rw    = (const float*)d_in[7];
    const float* cbias = (const float*)d_in[8];
    const float* gn    = (const float*)d_in[9];
    float* out = (float*)d_out;

    const size_t nBSD = (size_t)B_ * S_ * D_;              // 6291456
    ushort_t* xconv = (ushort_t*)d_ws;
    ushort_t* xb    = xconv + nBSD;
    ushort_t* G     = xb + nBSD;                           // S*NH*B*DH*4 = 25165824
    ushort_t* ys    = G + (size_t)S_ * NH_ * 4 * B_ * DH_; // 6291456

    conv_kernel<<<dim3(B_ * S_ * D_ / 4 / 256), dim3(256), 0, stream>>>(x, ck, cb, xconv, xb);
    gates_kernel<<<dim3(32, NH_, 2), dim3(768), 0, stream>>>(xconv, xb, Wi, Wf, Wz, Wo, cbias, G);
    recur_kernel<<<dim3(NH_ * B_), dim3(768), 0, stream>>>(G, Rw, ys);
    ln_kernel<<<dim3(8192), dim3(256), 0, stream>>>(ys, gn, out);
}

// Round 8
// 2106.705 us; speedup vs baseline: 1.0180x; 1.0180x over previous
//
#include <hip/hip_runtime.h>

#define B_  4
#define S_  2048
#define D_  768
#define NH_ 4
#define DH_ 192

typedef short  s8v __attribute__((ext_vector_type(8)));
typedef float  f4v __attribute__((ext_vector_type(4)));
typedef unsigned short ushort_t;

static __device__ __forceinline__ ushort_t f2bf(float f) {
    union { float f; unsigned u; } v; v.f = f;
    unsigned r = v.u + 0x7fffu + ((v.u >> 16) & 1u);
    return (ushort_t)(r >> 16);
}
static __device__ __forceinline__ float bf2f(ushort_t b) {
    union { unsigned u; float f; } v; v.u = ((unsigned)b) << 16;
    return v.f;
}
static __device__ __forceinline__ f4v mfma16(s8v a, s8v b, f4v c) {
    return __builtin_amdgcn_mfma_f32_16x16x32_bf16(a, b, c, 0, 0, 0);
}
// packed-bf16 dot2 into f32: D = a.lo*b.lo + a.hi*b.hi + c  (full vector rate)
static __device__ __forceinline__ float dot2bf(unsigned a, unsigned b, float c) {
    float d;
    asm("v_dot2_f32_bf16 %0, %1, %2, %3" : "=v"(d) : "v"(a), "v"(b), "v"(c));
    return d;
}
// sum across the 4 lanes of a quad (DPP quad_perm; pure VALU, no LDS pipe)
static __device__ __forceinline__ float qsum(float x) {
    union { float f; int i; } u, v;
    u.f = x;
    v.i = __builtin_amdgcn_mov_dpp(u.i, 0xB1, 0xF, 0xF, true);  // [1,0,3,2]
    x += v.f;
    u.f = x;
    v.i = __builtin_amdgcn_mov_dpp(u.i, 0x4E, 0xF, 0xF, true);  // [2,3,0,1]
    x += v.f;
    return x;
}

// ---------------------------------------------------------------------------
// Kernel 1: causal depthwise conv1d + swish -> x_conv (bf16); also x -> bf16.
// ---------------------------------------------------------------------------
__global__ void conv_kernel(const float* __restrict__ x, const float* __restrict__ ck,
                            const float* __restrict__ cb,
                            ushort_t* __restrict__ xconv, ushort_t* __restrict__ xb) {
    int idx = blockIdx.x * blockDim.x + threadIdx.x;   // over B*S*D/4
    const int nd4 = D_ / 4;
    int d4 = idx % nd4;
    int bs = idx / nd4;
    int s = bs % S_;
    int b = bs / S_;
    int d = d4 * 4;

    float4 acc = *(const float4*)(cb + d);
    float4 xcur = make_float4(0.f, 0.f, 0.f, 0.f);
#pragma unroll
    for (int k = 0; k < 4; ++k) {
        int sk = s - 3 + k;
        float4 xv = make_float4(0.f, 0.f, 0.f, 0.f);
        if (sk >= 0) xv = *(const float4*)(x + ((size_t)(b * S_ + sk) * D_ + d));
        if (k == 3) xcur = xv;
        float4 kv = *(const float4*)(ck + (size_t)k * D_ + d);
        acc.x += xv.x * kv.x; acc.y += xv.y * kv.y;
        acc.z += xv.z * kv.z; acc.w += xv.w * kv.w;
    }
    float c0 = acc.x / (1.f + __expf(-acc.x));
    float c1 = acc.y / (1.f + __expf(-acc.y));
    float c2 = acc.z / (1.f + __expf(-acc.z));
    float c3 = acc.w / (1.f + __expf(-acc.w));

    size_t base = (size_t)bs * D_ + d;
    ushort4 pc; pc.x = f2bf(c0); pc.y = f2bf(c1); pc.z = f2bf(c2); pc.w = f2bf(c3);
    *(ushort4*)(xconv + base) = pc;
    ushort4 px; px.x = f2bf(xcur.x); px.y = f2bf(xcur.y); px.z = f2bf(xcur.z); px.w = f2bf(xcur.w);
    *(ushort4*)(xb + base) = px;
}

// ---------------------------------------------------------------------------
// Kernel 2: gate pre-activation GEMMs (unchanged).
// G layout: [s][h][b][e][g] bf16 (g in {i,f,z,o}), cell_bias folded in.
// ---------------------------------------------------------------------------
__launch_bounds__(768)
__global__ void gates_kernel(const ushort_t* __restrict__ xconv, const ushort_t* __restrict__ xb,
                             const float* __restrict__ Wi, const float* __restrict__ Wf,
                             const float* __restrict__ Wz, const float* __restrict__ Wo,
                             const float* __restrict__ cbias, ushort_t* __restrict__ G) {
    int sb = blockIdx.x, h = blockIdx.y, p = blockIdx.z;
    const ushort_t* X = (p == 0) ? xconv : xb;
    const float* W0 = (p == 0) ? Wi : Wz;
    const float* W1 = (p == 0) ? Wf : Wo;

    int tid = threadIdx.x;
    int lane = tid & 63;
    int w = tid >> 6;                 // 0..11 = e-tile

    int col = w * 16 + (lane & 15);   // e
    int kq0 = (lane >> 4) * 8;

    s8v B0[6], B1[6];
#pragma unroll
    for (int kt = 0; kt < 6; ++kt) {
        const float* w0p = W0 + ((size_t)(h * DH_ + kt * 32 + kq0)) * DH_ + col;
        const float* w1p = W1 + ((size_t)(h * DH_ + kt * 32 + kq0)) * DH_ + col;
        s8v f0, f1;
#pragma unroll
        for (int j = 0; j < 8; ++j) {
            f0[j] = (short)f2bf(w0p[(size_t)j * DH_]);
            f1[j] = (short)f2bf(w1p[(size_t)j * DH_]);
        }
        B0[kt] = f0; B1[kt] = f1;
    }
    float bias0 = cbias[(size_t)(2 * p) * D_ + h * DH_ + col];
    float bias1 = cbias[(size_t)(2 * p + 1) * D_ + h * DH_ + col];

    int b_l = lane & 3;
    int ds_l = (lane >> 2) & 3;

    for (int mt = 0; mt < 16; ++mt) {
        int s = sb * 64 + mt * 4 + ds_l;
        const ushort_t* ap = X + ((size_t)(b_l * S_ + s) * D_ + h * DH_ + kq0);
        s8v A[6];
#pragma unroll
        for (int kt = 0; kt < 6; ++kt) A[kt] = *(const s8v*)(ap + kt * 32);
        f4v a0 = {0.f, 0.f, 0.f, 0.f}, a1 = {0.f, 0.f, 0.f, 0.f};
#pragma unroll
        for (int kt = 0; kt < 6; ++kt) {
            a0 = mfma16(A[kt], B0[kt], a0);
            a1 = mfma16(A[kt], B1[kt], a1);
        }
        int sro = sb * 64 + mt * 4 + (lane >> 4);
#pragma unroll
        for (int r = 0; r < 4; ++r) {
            size_t idx = (((size_t)(sro * NH_ + h) * B_ + r) * DH_ + col) * 4;
            ushort2 pr;
            pr.x = f2bf(a0[r] + bias0);
            pr.y = f2bf(a1[r] + bias1);
            *(ushort2*)(G + idx + 2 * p) = pr;
        }
    }
}

// ---------------------------------------------------------------------------
// Kernel 2b: one-time R repack: fp32 R[g][h][d][e] -> packed bf16-pair dwords
// Rp[(((g*4+h)*4+q)*192 + e)*24 + j] = pack(R[g][h][q*48+2j][e], R[..+1][e])
// so each recur lane's 24 dwords per gate are CONTIGUOUS (6 x dwordx4).
// ---------------------------------------------------------------------------
__global__ void rpack_kernel(const float* __restrict__ Rw, unsigned* __restrict__ Rp) {
    int idx = blockIdx.x * blockDim.x + threadIdx.x;   // over 4*4*4*192*24 = 294912
    int j  = idx % 24;
    int e  = (idx / 24) % 192;
    int q  = (idx / (24 * 192)) & 3;
    int gh = idx / (24 * 192 * 4);                     // g*4+h
    int d0 = q * 48 + 2 * j;
    const float* rp = Rw + ((size_t)gh * DH_ + d0) * DH_ + e;
    unsigned lo = f2bf(rp[0]);
    unsigned hi = f2bf(rp[DH_]);
    Rp[idx] = lo | (hi << 16);
}

// ---------------------------------------------------------------------------
// Kernel 3: sequential recurrence, v_dot2_f32_bf16, d-split + quad-reduce.
//
// Remat endgame (R3-R7: VGPR stuck at 64-84, weights re-derived every step;
// pins failed because the compiler may legally RECOMPUTE a pin's input before
// each execution). Fix: remove the derivation chain entirely --
//  - R is pre-packed to bf16-pair dwords by rpack_kernel (one-time, 1.2MB).
//  - recur loads them via asm VOLATILE global_load_dwordx4: the sole def of
//    each Bf dword is an opaque volatile asm. Recompute = re-executing a
//    volatile asm (forbidden); a fresh non-asm reload is not provably equal.
//    RA must keep 96 dwords resident (live set ~145 < 170 budget at
//    waves_per_eu(3,3)) or scratch-spill (loudly visible).
// Structure (unchanged from R3-R7):
//  - 16 WGs (one per (b,h)), 768 thr = 12 waves = exactly 3 waves/SIMD;
//    dot2 issue floor = 147456 MACs / 256 MACs/cyc = 576 cyc/step.
//  - thread (e, q=lane&3) owns d-quarter q of all 4 gates' R columns.
//  - h reads: quad-broadcast, bank groups per q disjoint -> conflict-free.
//  - quad partials reduced with 2 mov_dpp quad_perm + adds; quad leader
//    writes h (LDS) + ys (global).
//  - 2-deep G prefetch; one lgkm-only barrier per step.
// GATES: success = VGPR 130-170 & recur < 1000us. Failure -> R1 revert, final.
// ---------------------------------------------------------------------------
#define GLD(dst, ptr) \
    asm volatile("global_load_dwordx4 %0, %1, off" : "=v"(dst) : "v"(ptr) : "memory")

#define DOTK(H, RI, RF, RZ, RO) do { \
    ai = dot2bf(H.x, RI.x, ai); af = dot2bf(H.x, RF.x, af); \
    az = dot2bf(H.x, RZ.x, az); ao = dot2bf(H.x, RO.x, ao); \
    ai = dot2bf(H.y, RI.y, ai); af = dot2bf(H.y, RF.y, af); \
    az = dot2bf(H.y, RZ.y, az); ao = dot2bf(H.y, RO.y, ao); \
    ai = dot2bf(H.z, RI.z, ai); af = dot2bf(H.z, RF.z, af); \
    az = dot2bf(H.z, RZ.z, az); ao = dot2bf(H.z, RO.z, ao); \
    ai = dot2bf(H.w, RI.w, ai); af = dot2bf(H.w, RF.w, af); \
    az = dot2bf(H.w, RZ.w, az); ao = dot2bf(H.w, RO.w, ao); \
} while (0)

#define STEP(p) do { \
    const uint4* hbp = (const uint4*)((const char*)h_lds + (p) * 384 + q * 96); \
    uint4 H0 = hbp[0], H1 = hbp[1], H2 = hbp[2], H3 = hbp[3], H4 = hbp[4], H5 = hbp[5]; \
    float ai = 0.f, af = 0.f, az = 0.f, ao = 0.f; \
    DOTK(H0, Ri0, Rf0, Rz0, Ro0); \
    DOTK(H1, Ri1, Rf1, Rz1, Ro1); \
    DOTK(H2, Ri2, Rf2, Rz2, Ro2); \
    DOTK(H3, Ri3, Rf3, Rz3, Ro3); \
    DOTK(H4, Ri4, Rf4, Rz4, Ro4); \
    DOTK(H5, Ri5, Rf5, Rz5, Ro5); \
    ai = qsum(ai); af = qsum(af); az = qsum(az); ao = qsum(ao); \
    ushort4 gv = gv_n; gv_n = gv_n2; \
    gv_n2 = *(const ushort4*)gp; gp += gstride; \
    ai += bf2f(gv.x); af += bf2f(gv.y); az += bf2f(gv.z); ao += bf2f(gv.w); \
    float fm = af + m_st; \
    float mn = fmaxf(fm, ai); \
    float ia = __builtin_amdgcn_exp2f((ai - mn) * LOG2E); \
    float fa = __builtin_amdgcn_exp2f((fm - mn) * LOG2E); \
    float ez = __builtin_amdgcn_exp2f(az * (2.f * LOG2E)); \
    float th = 1.f - 2.f * __builtin_amdgcn_rcpf(ez + 1.f); \
    float cn = fa * c_st + ia * th; \
    float nn = fa * n_st + ia; \
    float sg = __builtin_amdgcn_rcpf(1.f + __builtin_amdgcn_exp2f(-ao * LOG2E)); \
    float hn = sg * cn * __builtin_amdgcn_rcpf(nn); \
    m_st = mn; c_st = cn; n_st = nn; \
    ushort_t hb16 = f2bf(hn); \
    if (qlead) h_flat[(1 - (p)) * 192 + e] = hb16; \
    asm volatile("s_waitcnt lgkmcnt(0)\n\ts_barrier" ::: "memory"); \
    if (qlead) *yp = hb16; \
    yp += ystr; \
} while (0)

__global__ void __launch_bounds__(768)
__attribute__((amdgpu_waves_per_eu(3, 3)))
recur_kernel(const ushort_t* __restrict__ G, const unsigned* __restrict__ Rp,
             ushort_t* __restrict__ ys) {
    const int h = blockIdx.x >> 2;
    const int b = blockIdx.x & 3;
    const int tid = threadIdx.x;
    const int lane = tid & 63;
    const int w = tid >> 6;                     // 0..11
    const int e = w * 16 + (lane >> 2);         // 0..191  (column this thread serves)
    const int q = lane & 3;                     // d-quarter: d in [q*48, q*48+48)
    const bool qlead = (q == 0);

    __shared__ __align__(16) ushort_t h_lds[2][192];
    ushort_t* h_flat = &h_lds[0][0];

    // Bf: 4 gates x 24 packed dwords, loaded ONCE via volatile asm (opaque
    // defs -> not rematerializable). Lane base: (((g*4+h)*4+q)*192 + e)*24.
    uint4 Ri0, Ri1, Ri2, Ri3, Ri4, Ri5;
    uint4 Rf0, Rf1, Rf2, Rf3, Rf4, Rf5;
    uint4 Rz0, Rz1, Rz2, Rz3, Rz4, Rz5;
    uint4 Ro0, Ro1, Ro2, Ro3, Ro4, Ro5;
    {
        const unsigned* p0 = Rp + ((size_t)(((0 * 4 + h) * 4 + q) * 192 + e)) * 24;
        const unsigned* p1 = Rp + ((size_t)(((1 * 4 + h) * 4 + q) * 192 + e)) * 24;
        const unsigned* p2 = Rp + ((size_t)(((2 * 4 + h) * 4 + q) * 192 + e)) * 24;
        const unsigned* p3 = Rp + ((size_t)(((3 * 4 + h) * 4 + q) * 192 + e)) * 24;
        GLD(Ri0, p0 +  0); GLD(Ri1, p0 +  4); GLD(Ri2, p0 +  8);
        GLD(Ri3, p0 + 12); GLD(Ri4, p0 + 16); GLD(Ri5, p0 + 20);
        GLD(Rf0, p1 +  0); GLD(Rf1, p1 +  4); GLD(Rf2, p1 +  8);
        GLD(Rf3, p1 + 12); GLD(Rf4, p1 + 16); GLD(Rf5, p1 + 20);
        GLD(Rz0, p2 +  0); GLD(Rz1, p2 +  4); GLD(Rz2, p2 +  8);
        GLD(Rz3, p2 + 12); GLD(Rz4, p2 + 16); GLD(Rz5, p2 + 20);
        GLD(Ro0, p3 +  0); GLD(Ro1, p3 +  4); GLD(Ro2, p3 +  8);
        GLD(Ro3, p3 + 12); GLD(Ro4, p3 + 16); GLD(Ro5, p3 + 20);
        asm volatile("s_waitcnt vmcnt(0)" ::: "memory");
    }

    if (tid < 384) h_flat[tid] = 0;

    float m_st = 0.f, c_st = 0.f, n_st = 0.f;
    const float LOG2E = 1.44269504088896f;

    const int gstride = NH_ * B_ * DH_ * 4;     // 12288 ushorts per s
    const ushort_t* gp = G + (((size_t)h * B_ + b) * DH_ + e) * 4;
    // 2-deep prefetch; over-reads at s=S_,S_+1 land in the ys region (mapped).
    ushort4 gv_n  = *(const ushort4*)gp;
    ushort4 gv_n2 = *(const ushort4*)(gp + gstride);
    gp += 2 * (size_t)gstride;

    ushort_t* yp = ys + ((size_t)h * B_ + b) * DH_ + e;
    const int ystr = NH_ * B_ * DH_;

    __syncthreads();

    for (int s = 0; s < S_; s += 2) {
        STEP(0);
        STEP(1);
    }
}

// ---------------------------------------------------------------------------
// Kernel 4: multi-head layernorm. One wave per (b,s,h) group of 192.
// ---------------------------------------------------------------------------
__global__ void ln_kernel(const ushort_t* __restrict__ ys, const float* __restrict__ gn,
                          float* __restrict__ out) {
    int gw = (blockIdx.x * blockDim.x + threadIdx.x) >> 6;   // 0 .. 32767
    int lane = threadIdx.x & 63;
    int b = gw & 3;
    int h = (gw >> 2) & 3;
    int s = gw >> 4;

    const ushort_t* yp = ys + (size_t)gw * DH_;
    float v0 = bf2f(yp[lane]);
    float v1 = bf2f(yp[lane + 64]);
    float v2 = bf2f(yp[lane + 128]);
    float sum = v0 + v1 + v2;
    float sq  = v0 * v0 + v1 * v1 + v2 * v2;
#pragma unroll
    for (int off = 32; off > 0; off >>= 1) {
        sum += __shfl_xor(sum, off, 64);
        sq  += __shfl_xor(sq,  off, 64);
    }
    float mu  = sum * (1.f / 192.f);
    float var = sq * (1.f / 192.f) - mu * mu;
    float rs  = rsqrtf(var + 1e-5f);

    float* op = out + (size_t)(b * S_ + s) * D_ + h * DH_;
    const float* gp = gn + h * DH_;
    op[lane]       = (v0 - mu) * rs * gp[lane];
    op[lane + 64]  = (v1 - mu) * rs * gp[lane + 64];
    op[lane + 128] = (v2 - mu) * rs * gp[lane + 128];
}

// ---------------------------------------------------------------------------
extern "C" void kernel_launch(void* const* d_in, const int* in_sizes, int n_in,
                              void* d_out, int out_size, void* d_ws, size_t ws_size,
                              hipStream_t stream) {
    const float* x     = (const float*)d_in[0];
    const float* ck    = (const float*)d_in[1];
    const float* cb    = (const float*)d_in[2];
    const float* Wi    = (const float*)d_in[3];
    const float* Wf    = (const float*)d_in[4];
    const float* Wz    = (const float*)d_in[5];
    const float* Wo    = (const float*)d_in[6];
    const float* Rw    = (const float*)d_in[7];
    const float* cbias = (const float*)d_in[8];
    const float* gn    = (const float*)d_in[9];
    float* out = (float*)d_out;

    const size_t nBSD = (size_t)B_ * S_ * D_;              // 6291456
    ushort_t* xconv = (ushort_t*)d_ws;
    ushort_t* xb    = xconv + nBSD;
    ushort_t* G     = xb + nBSD;                           // S*NH*B*DH*4 = 25165824
    ushort_t* ys    = G + (size_t)S_ * NH_ * 4 * B_ * DH_; // 6291456
    // Rp (1.18 MB) overlays xconv -- dead after gates_kernel completes.
    unsigned* Rp    = (unsigned*)xconv;

    conv_kernel<<<dim3(B_ * S_ * D_ / 4 / 256), dim3(256), 0, stream>>>(x, ck, cb, xconv, xb);
    gates_kernel<<<dim3(32, NH_, 2), dim3(768), 0, stream>>>(xconv, xb, Wi, Wf, Wz, Wo, cbias, G);
    rpack_kernel<<<dim3(294912 / 256), dim3(256), 0, stream>>>(Rw, Rp);
    recur_kernel<<<dim3(NH_ * B_), dim3(768), 0, stream>>>(G, Rp, ys);
    ln_kernel<<<dim3(8192), dim3(256), 0, stream>>>(ys, gn, out);
}

// Round 9
// 1661.700 us; speedup vs baseline: 1.2906x; 1.2678x over previous
//
#include <hip/hip_runtime.h>

#define B_  4
#define S_  2048
#define D_  768
#define NH_ 4
#define DH_ 192

typedef short  s8v __attribute__((ext_vector_type(8)));
typedef float  f4v __attribute__((ext_vector_type(4)));
typedef unsigned short ushort_t;

static __device__ __forceinline__ ushort_t f2bf(float f) {
    union { float f; unsigned u; } v; v.f = f;
    unsigned r = v.u + 0x7fffu + ((v.u >> 16) & 1u);
    return (ushort_t)(r >> 16);
}
static __device__ __forceinline__ float bf2f(ushort_t b) {
    union { unsigned u; float f; } v; v.u = ((unsigned)b) << 16;
    return v.f;
}
static __device__ __forceinline__ f4v mfma16(s8v a, s8v b, f4v c) {
    return __builtin_amdgcn_mfma_f32_16x16x32_bf16(a, b, c, 0, 0, 0);
}

// ---------------------------------------------------------------------------
// Kernel 1: causal depthwise conv1d + swish -> x_conv (bf16); also x -> bf16.
// ---------------------------------------------------------------------------
__global__ void conv_kernel(const float* __restrict__ x, const float* __restrict__ ck,
                            const float* __restrict__ cb,
                            ushort_t* __restrict__ xconv, ushort_t* __restrict__ xb) {
    int idx = blockIdx.x * blockDim.x + threadIdx.x;   // over B*S*D/4
    const int nd4 = D_ / 4;
    int d4 = idx % nd4;
    int bs = idx / nd4;
    int s = bs % S_;
    int b = bs / S_;
    int d = d4 * 4;

    float4 acc = *(const float4*)(cb + d);
    float4 xcur = make_float4(0.f, 0.f, 0.f, 0.f);
#pragma unroll
    for (int k = 0; k < 4; ++k) {
        int sk = s - 3 + k;
        float4 xv = make_float4(0.f, 0.f, 0.f, 0.f);
        if (sk >= 0) xv = *(const float4*)(x + ((size_t)(b * S_ + sk) * D_ + d));
        if (k == 3) xcur = xv;
        float4 kv = *(const float4*)(ck + (size_t)k * D_ + d);
        acc.x += xv.x * kv.x; acc.y += xv.y * kv.y;
        acc.z += xv.z * kv.z; acc.w += xv.w * kv.w;
    }
    float c0 = acc.x / (1.f + __expf(-acc.x));
    float c1 = acc.y / (1.f + __expf(-acc.y));
    float c2 = acc.z / (1.f + __expf(-acc.z));
    float c3 = acc.w / (1.f + __expf(-acc.w));

    size_t base = (size_t)bs * D_ + d;
    ushort4 pc; pc.x = f2bf(c0); pc.y = f2bf(c1); pc.z = f2bf(c2); pc.w = f2bf(c3);
    *(ushort4*)(xconv + base) = pc;
    ushort4 px; px.x = f2bf(xcur.x); px.y = f2bf(xcur.y); px.z = f2bf(xcur.z); px.w = f2bf(xcur.w);
    *(ushort4*)(xb + base) = px;
}

// ---------------------------------------------------------------------------
// Kernel 2: gate pre-activation GEMMs.
// G layout: [s][h][b][e][g] bf16 (g in {i,f,z,o}), cell_bias folded in.
// grid: (32 s-blocks, NH, 2) ; p=0 -> {i,f} from x_conv ; p=1 -> {z,o} from x.
// ---------------------------------------------------------------------------
__launch_bounds__(768)
__global__ void gates_kernel(const ushort_t* __restrict__ xconv, const ushort_t* __restrict__ xb,
                             const float* __restrict__ Wi, const float* __restrict__ Wf,
                             const float* __restrict__ Wz, const float* __restrict__ Wo,
                             const float* __restrict__ cbias, ushort_t* __restrict__ G) {
    int sb = blockIdx.x, h = blockIdx.y, p = blockIdx.z;
    const ushort_t* X = (p == 0) ? xconv : xb;
    const float* W0 = (p == 0) ? Wi : Wz;
    const float* W1 = (p == 0) ? Wf : Wo;

    int tid = threadIdx.x;
    int lane = tid & 63;
    int w = tid >> 6;                 // 0..11 = e-tile

    int col = w * 16 + (lane & 15);   // e
    int kq0 = (lane >> 4) * 8;

    s8v B0[6], B1[6];
#pragma unroll
    for (int kt = 0; kt < 6; ++kt) {
        const float* w0p = W0 + ((size_t)(h * DH_ + kt * 32 + kq0)) * DH_ + col;
        const float* w1p = W1 + ((size_t)(h * DH_ + kt * 32 + kq0)) * DH_ + col;
        s8v f0, f1;
#pragma unroll
        for (int j = 0; j < 8; ++j) {
            f0[j] = (short)f2bf(w0p[(size_t)j * DH_]);
            f1[j] = (short)f2bf(w1p[(size_t)j * DH_]);
        }
        B0[kt] = f0; B1[kt] = f1;
    }
    float bias0 = cbias[(size_t)(2 * p) * D_ + h * DH_ + col];
    float bias1 = cbias[(size_t)(2 * p + 1) * D_ + h * DH_ + col];

    int b_l = lane & 3;
    int ds_l = (lane >> 2) & 3;

    for (int mt = 0; mt < 16; ++mt) {
        int s = sb * 64 + mt * 4 + ds_l;
        const ushort_t* ap = X + ((size_t)(b_l * S_ + s) * D_ + h * DH_ + kq0);
        s8v A[6];
#pragma unroll
        for (int kt = 0; kt < 6; ++kt) A[kt] = *(const s8v*)(ap + kt * 32);
        f4v a0 = {0.f, 0.f, 0.f, 0.f}, a1 = {0.f, 0.f, 0.f, 0.f};
#pragma unroll
        for (int kt = 0; kt < 6; ++kt) {
            a0 = mfma16(A[kt], B0[kt], a0);
            a1 = mfma16(A[kt], B1[kt], a1);
        }
        // epilogue: C row = (lane>>4)*4 + r ; r = batch, lane>>4 = s offset
        int sro = sb * 64 + mt * 4 + (lane >> 4);
#pragma unroll
        for (int r = 0; r < 4; ++r) {
            size_t idx = (((size_t)(sro * NH_ + h) * B_ + r) * DH_ + col) * 4;
            ushort2 pr;
            pr.x = f2bf(a0[r] + bias0);
            pr.y = f2bf(a1[r] + bias1);
            *(ushort2*)(G + idx + 2 * p) = pr;
        }
    }
}

// ---------------------------------------------------------------------------
// Kernel 3: sequential recurrence. One WG per head. 768 thr = 12 waves.
// Batch b occupies A-rows 4b..4b+3 (content h[row>>2]) so C-row 4b lands in
// lane 16b reg 0 -> every lane holds its own (b,e) pre-acts for all 4 gates.
//
// This revision targets the ~830-cyc/step gap above the 1397-cyc MFMA floor:
//  - gv (gate pre-acts) folded into MFMA C-init: saves 16 v_mov + 4 v_add
//    per wave-step (rows 1-3 of C are replicated-batch garbage, never read).
//  - G prefetch 2 steps ahead via rotating regs (unroll renames them away):
//    the consumed value is always >= 2 full steps old -> no vmcnt stall.
//  - ys stores batched 8-per-block in statically-indexed regs: 7 of 8 steps
//    have a pure-load vmcnt queue, store-ack latency amortized 8x.
//  - gating VALU interleaved between gate MFMA chains (f,i -> exp; z -> c,n;
//    o -> h) so the scalar tail overlaps MFMA issue.
// Raw lgkm-only barrier per step (ys stores need no ordering); double-buffered
// h in LDS. ys layout: [s][h][b][e] bf16.
// ---------------------------------------------------------------------------
__launch_bounds__(768)
__global__ void recur_kernel(const ushort_t* __restrict__ G, const float* __restrict__ Rw,
                             ushort_t* __restrict__ ys) {
    const int h = blockIdx.x;
    const int tid = threadIdx.x;
    const int lane = tid & 63;
    const int w = tid >> 6;

    __shared__ ushort_t h_lds[2 * 4 * 208];   // two buffers, [b][e] stride 208

    // R fragments: B[k=(lane>>4)*8+j][e = w*16 + (lane&15)]
    s8v Bf[4][6];
    {
        int col = w * 16 + (lane & 15);
        int kq0 = (lane >> 4) * 8;
#pragma unroll
        for (int g = 0; g < 4; ++g)
#pragma unroll
            for (int kt = 0; kt < 6; ++kt) {
                const float* rp = Rw + ((size_t)((g * NH_ + h) * DH_ + kt * 32 + kq0)) * DH_ + col;
                s8v f;
#pragma unroll
                for (int j = 0; j < 8; ++j) f[j] = (short)f2bf(rp[(size_t)j * DH_]);
                Bf[g][kt] = f;
            }
    }

    for (int i = tid; i < 2 * 4 * 208; i += 768) h_lds[i] = 0;

    const int b_id = lane >> 4;                 // batch this lane gates
    const int e_id = w * 16 + (lane & 15);      // e-column this lane gates
    const int a_off = ((lane & 15) >> 2) * 208 + (lane >> 4) * 8;  // A-frag elem offset
    const int hw_off = b_id * 208 + e_id;       // h-write elem offset in buffer

    float m_st = 0.f, c_st = 0.f, n_st = 0.f;
    const float LOG2E = 1.44269504088896f;

    const int gstride = NH_ * B_ * DH_ * 4;     // 12288 ushorts per s
    const ushort_t* gp = G + (((size_t)h * B_ + b_id) * DH_ + e_id) * 4;
    // 2-deep prefetch pipeline. Over-reads at s = S_, S_+1 land in the ys
    // region of the workspace (mapped, value unused) -> no tail branch.
    ushort4 gv_n  = *(const ushort4*)gp;
    ushort4 gv_n2 = *(const ushort4*)(gp + gstride);
    gp += 2 * (size_t)gstride;

    ushort_t* yp = ys + ((size_t)h * B_ + b_id) * DH_ + e_id;   // s-stride 3072
    const int ystr = NH_ * B_ * DH_;

    __syncthreads();

    for (int sb = 0; sb < S_; sb += 8) {
        ushort_t hbv[8];                        // statically indexed (unrolled)
#pragma unroll
        for (int si = 0; si < 8; ++si) {
            const int s = sb + si;
            ushort4 gv = gv_n;                  // >= 2 steps old: never stalls
            gv_n = gv_n2;
            gv_n2 = *(const ushort4*)gp;        // prefetch s+2
            gp += gstride;

            const int p = s & 1;
            const ushort_t* abuf = h_lds + p * 832 + a_off;

            s8v A[6];
#pragma unroll
            for (int kt = 0; kt < 6; ++kt)
                A[kt] = *(const s8v*)(abuf + kt * 32);

            // f and i gates first: they head the gating dependency chain.
            // gv folded into C-init (reg 0 is this lane's row; 1..3 unused).
            f4v accF = {bf2f(gv.y), 0.f, 0.f, 0.f};
            f4v accI = {bf2f(gv.x), 0.f, 0.f, 0.f};
#pragma unroll
            for (int kt = 0; kt < 6; ++kt) accF = mfma16(A[kt], Bf[1][kt], accF);
#pragma unroll
            for (int kt = 0; kt < 6; ++kt) accI = mfma16(A[kt], Bf[0][kt], accI);

            float fm = accF[0] + m_st;
            float it = accI[0];
            float mn = fmaxf(fm, it);
            float ia = __builtin_amdgcn_exp2f((it - mn) * LOG2E);
            float fa = __builtin_amdgcn_exp2f((fm - mn) * LOG2E);

            f4v accZ = {bf2f(gv.z), 0.f, 0.f, 0.f};
#pragma unroll
            for (int kt = 0; kt < 6; ++kt) accZ = mfma16(A[kt], Bf[2][kt], accZ);
            float ez = __builtin_amdgcn_exp2f(accZ[0] * (2.f * LOG2E));
            float th = 1.f - 2.f * __builtin_amdgcn_rcpf(ez + 1.f);
            float cn = fa * c_st + ia * th;
            float nn = fa * n_st + ia;

            f4v accO = {bf2f(gv.w), 0.f, 0.f, 0.f};
#pragma unroll
            for (int kt = 0; kt < 6; ++kt) accO = mfma16(A[kt], Bf[3][kt], accO);
            float sg = __builtin_amdgcn_rcpf(1.f + __builtin_amdgcn_exp2f(-accO[0] * LOG2E));
            float hn = sg * cn * __builtin_amdgcn_rcpf(nn);
            m_st = mn; c_st = cn; n_st = nn;

            ushort_t hb = f2bf(hn);
            hbv[si] = hb;
            h_lds[(1 - p) * 832 + hw_off] = hb; // write next step's h buffer

            // lgkm-only barrier: orders the LDS ping-pong without draining
            // the global queues (ys stores / G prefetch need no ordering).
            asm volatile("s_waitcnt lgkmcnt(0)\n\ts_barrier" ::: "memory");
        }
        // batched ys stores: off the per-step vmcnt-critical path entirely
#pragma unroll
        for (int si = 0; si < 8; ++si)
            yp[(size_t)si * ystr] = hbv[si];
        yp += (size_t)8 * ystr;
    }
}

// ---------------------------------------------------------------------------
// Kernel 4: multi-head layernorm. One wave per (b,s,h) group of 192.
// ---------------------------------------------------------------------------
__global__ void ln_kernel(const ushort_t* __restrict__ ys, const float* __restrict__ gn,
                          float* __restrict__ out) {
    int gw = (blockIdx.x * blockDim.x + threadIdx.x) >> 6;   // 0 .. 32767
    int lane = threadIdx.x & 63;
    int b = gw & 3;
    int h = (gw >> 2) & 3;
    int s = gw >> 4;

    const ushort_t* yp = ys + (size_t)gw * DH_;
    float v0 = bf2f(yp[lane]);
    float v1 = bf2f(yp[lane + 64]);
    float v2 = bf2f(yp[lane + 128]);
    float sum = v0 + v1 + v2;
    float sq  = v0 * v0 + v1 * v1 + v2 * v2;
#pragma unroll
    for (int off = 32; off > 0; off >>= 1) {
        sum += __shfl_xor(sum, off, 64);
        sq  += __shfl_xor(sq,  off, 64);
    }
    float mu  = sum * (1.f / 192.f);
    float var = sq * (1.f / 192.f) - mu * mu;
    float rs  = rsqrtf(var + 1e-5f);

    float* op = out + (size_t)(b * S_ + s) * D_ + h * DH_;
    const float* gp = gn + h * DH_;
    op[lane]       = (v0 - mu) * rs * gp[lane];
    op[lane + 64]  = (v1 - mu) * rs * gp[lane + 64];
    op[lane + 128] = (v2 - mu) * rs * gp[lane + 128];
}

// ---------------------------------------------------------------------------
extern "C" void kernel_launch(void* const* d_in, const int* in_sizes, int n_in,
                              void* d_out, int out_size, void* d_ws, size_t ws_size,
                              hipStream_t stream) {
    const float* x     = (const float*)d_in[0];
    const float* ck    = (const float*)d_in[1];
    const float* cb    = (const float*)d_in[2];
    const float* Wi    = (const float*)d_in[3];
    const float* Wf    = (const float*)d_in[4];
    const float* Wz    = (const float*)d_in[5];
    const float* Wo    = (const float*)d_in[6];
    const float* Rw    = (const float*)d_in[7];
    const float* cbias = (const float*)d_in[8];
    const float* gn    = (const float*)d_in[9];
    float* out = (float*)d_out;

    const size_t nBSD = (size_t)B_ * S_ * D_;              // 6291456
    ushort_t* xconv = (ushort_t*)d_ws;
    ushort_t* xb    = xconv + nBSD;
    ushort_t* G     = xb + nBSD;                           // S*NH*B*DH*4 = 25165824
    ushort_t* ys    = G + (size_t)S_ * NH_ * 4 * B_ * DH_; // 6291456

    conv_kernel<<<dim3(B_ * S_ * D_ / 4 / 256), dim3(256), 0, stream>>>(x, ck, cb, xconv, xb);
    gates_kernel<<<dim3(32, NH_, 2), dim3(768), 0, stream>>>(xconv, xb, Wi, Wf, Wz, Wo, cbias, G);
    recur_kernel<<<dim3(NH_), dim3(768), 0, stream>>>(G, Rw, ys);
    ln_kernel<<<dim3(8192), dim3(256), 0, stream>>>(ys, gn, out);
}